// Round 22
// baseline (183.691 us; speedup 1.0000x reference)
//
#include <hip/hip_runtime.h>
#include <hip/hip_bf16.h>
#include <stdint.h>

// B=4, S=8192, E=1024, heads=16 -> math collapses to:
//   Q = x @ W1[0:1024].T ; A = per-64-col-block softmax(Q/4) ; out = A @ W2.T
static constexpr int MTOT = 32768;
static constexpr int KD   = 1024;
static constexpr int ND   = 1024;

static constexpr int BM = 256, BN = 256, BK = 64;
static constexpr int NT = KD / BK;              // 16 K-tiles (even)
static constexpr int BUF_BYTES = 65536;         // per-buffer: A 32K + B 32K
static constexpr int BOFF = 32768;              // B offset within buffer
static constexpr int HALF = 16384;              // one unit (128 rows x 64 cols bf16)

typedef __bf16 bf16x8 __attribute__((ext_vector_type(8)));
typedef float  f32x4  __attribute__((ext_vector_type(4)));

__device__ __forceinline__ unsigned short f2bf_rne(float f) {
  union { float f; uint32_t u; } c; c.f = f;
  uint32_t u = c.u;
  return (unsigned short)((u + 0x7fffu + ((u >> 16) & 1u)) >> 16);
}

// One kernel for all three casts (x, W1q, W2).
__global__ void cast_all(const float* __restrict__ x,
                         const float* __restrict__ W1,
                         const float* __restrict__ W2,
                         unsigned short* __restrict__ xb,
                         unsigned short* __restrict__ w1b,
                         unsigned short* __restrict__ w2b) {
  constexpr int n4x = MTOT * KD / 4;
  constexpr int n4w = KD * KD / 4;
  constexpr int total = n4x + 2 * n4w;
  int idx = blockIdx.x * blockDim.x + threadIdx.x;
  int stride = gridDim.x * blockDim.x;
  for (int i = idx; i < total; i += stride) {
    const float* s; unsigned short* d; int j;
    if (i < n4x)            { s = x;  d = xb;  j = i; }
    else if (i < n4x + n4w) { s = W1; d = w1b; j = i - n4x; }
    else                    { s = W2; d = w2b; j = i - n4x - n4w; }
    float4 v = reinterpret_cast<const float4*>(s)[j];
    ushort4 o;
    o.x = f2bf_rne(v.x); o.y = f2bf_rne(v.y);
    o.z = f2bf_rne(v.z); o.w = f2bf_rne(v.w);
    reinterpret_cast<ushort4*>(d)[j] = o;
  }
}

__device__ __forceinline__ void gload_lds16(const void* g, void* lds) {
  __builtin_amdgcn_global_load_lds(
      (const __attribute__((address_space(1))) unsigned int*)g,
      (__attribute__((address_space(3))) unsigned int*)lds, 16, 0, 0);
}

// r22 = r21 (session best, 181.2us) minus s_setprio around MFMA clusters.
// T5 evidence (m190 within-probe A/B): setprio is ~0 to NEGATIVE on lockstep
// GEMM structures (pays only on 8-phase role-split schedules). Our 4-phase
// lockstep loop executed 64 setprio pairs/wave/K-loop for nothing.
// Everything else r21-exact: 256x256, BK=64, 8 waves, 128 KiB dbuf LDS,
// T1 XCD swizzle, T2 LDS swizzle, FULL K-loop unroll (compile-time kt ->
// clamps and stage offsets fold to immediates), hoisted lane-constant
// read-swizzle (swzk0/swzk1), counted vmcnt (never 0), 3 barriers/tile
// {P2-end, P4-pre(post-vmcnt), P4-end}, r15 epilogues.
template <int SOFTMAX>
__global__ __launch_bounds__(512, 2)
void gemm8(const unsigned short* __restrict__ A,
           const unsigned short* __restrict__ Bm,
           void* __restrict__ Cout) {
  extern __shared__ __align__(16) char ldsc[];

  const int tid  = threadIdx.x;
  const int lane = tid & 63;
  const int wid  = tid >> 6;
  const int wm = wid >> 2, wn = wid & 3;       // wave tile: 128 rows x 64 cols
  const int fr = lane & 15, fq = lane >> 4;

  // T1: bijective XCD swizzle (512 blocks, 8 XCDs, 64 blocks/chunk).
  const int bid0 = blockIdx.x;
  const int bid  = ((bid0 & 7) << 6) | (bid0 >> 3);
  const int brow = (bid >> 2) * BM;
  const int bcol = (bid & 3) * BN;

  // staging: linear LDS dest + inverse-swizzled global src (rule #21).
  const int srow  = tid >> 3;                              // 0..63
  const int sslot = (tid & 7) ^ (srow & 7);
  const unsigned short* gA = A  + (size_t)(brow + srow) * KD + sslot * 8;
  const unsigned short* gB = Bm + (size_t)(bcol + srow) * KD + sslot * 8;

  // Hoisted lane-constant read-swizzle offsets.
  const int swzk0 = (fq * 16) ^ ((fr & 7) << 4);          // ks = 0
  const int swzk1 = (64 + fq * 16) ^ ((fr & 7) << 4);     // ks = 1

  f32x4  acc[8][4] = {};
  bf16x8 a0[4][2], a1[4][2], bA[2][2], bB[2][2];

  auto STAGE = [&](const unsigned short* g, int h, int kt, int b, int opOff) {
    const unsigned short* gu = g + (size_t)(h * 128) * KD + kt * BK;
    char* du = ldsc + b * BUF_BYTES + opOff + h * HALF + (wid << 10);
    gload_lds16(gu, du);
    gload_lds16(gu + (size_t)64 * KD, du + 8192);
  };

  auto rdA = [&](int b, bf16x8 (*dst)[2], int mBase) {
    const char* base = ldsc + b * BUF_BYTES + wm * HALF + (fr << 7);
    #pragma unroll
    for (int mm = 0; mm < 4; ++mm) {
      dst[mm][0] = *(const bf16x8*)(base + (mBase + mm) * 2048 + swzk0);
      dst[mm][1] = *(const bf16x8*)(base + (mBase + mm) * 2048 + swzk1);
    }
  };
  auto rdB = [&](int b, int nBase, bf16x8 (*dst)[2]) {
    const char* base = ldsc + b * BUF_BYTES + BOFF + (wn >> 1) * HALF +
                       (((wn & 1) * 64 + fr) << 7);
    #pragma unroll
    for (int nn = 0; nn < 2; ++nn) {
      dst[nn][0] = *(const bf16x8*)(base + (nBase + nn) * 2048 + swzk0);
      dst[nn][1] = *(const bf16x8*)(base + (nBase + nn) * 2048 + swzk1);
    }
  };
  auto MFMA16 = [&](int mBase, int nBase, bf16x8 (*af)[2], bf16x8 (*bf)[2]) {
    #pragma unroll
    for (int ks = 0; ks < 2; ++ks)
      #pragma unroll
      for (int mm = 0; mm < 4; ++mm)
        #pragma unroll
        for (int nn = 0; nn < 2; ++nn)
          acc[mBase + mm][nBase + nn] = __builtin_amdgcn_mfma_f32_16x16x32_bf16(
              af[mm][ks], bf[nn][ks], acc[mBase + mm][nBase + nn], 0, 0, 0);
  };

  // r15-exact K-tile step. Barriers: P2-end, P4-pre(post-vmcnt), P4-end.
  auto tileStep = [&](int T, int cur, int nxt) {
    const int tp1 = (T + 1 < NT) ? T + 1 : NT - 1;   // compile-time (unrolled)
    const int tp2 = (T + 2 < NT) ? T + 2 : NT - 1;

    rdA(cur, a0, 0);
    STAGE(gB, 0, tp1, nxt, BOFF);
    MFMA16(0, 0, a0, bA);

    rdA(cur, a1, 4);
    STAGE(gB, 1, tp1, nxt, BOFF);
    MFMA16(4, 0, a1, bA);
    __builtin_amdgcn_s_barrier();            // P2-end: all cur.A reads retired

    rdB(cur, 2, bB);
    STAGE(gA, 0, tp2, cur, 0);
    MFMA16(4, 2, a1, bB);

    STAGE(gA, 1, tp2, cur, 0);
    asm volatile("s_waitcnt vmcnt(4)" ::: "memory"); // retires thru T+1; T+2.A flies
    __builtin_amdgcn_s_barrier();            // P4-pre: tile T+1 visible to all
    rdB(nxt, 0, bA);                         // tile T+1 b01; overlaps MFMA below
    MFMA16(0, 2, a0, bB);
    __builtin_amdgcn_s_barrier();            // P4-end
  };

  // --- prologue: tile0 (4 units) + A halves of tile1 ---
  STAGE(gA, 0, 0, 0, 0);    STAGE(gA, 1, 0, 0, 0);
  STAGE(gB, 0, 0, 0, BOFF); STAGE(gB, 1, 0, 0, BOFF);
  STAGE(gA, 0, 1, 1, 0);    STAGE(gA, 1, 1, 1, 0);
  asm volatile("s_waitcnt vmcnt(4)" ::: "memory");   // tile0 landed; A(1) in flight
  __builtin_amdgcn_s_barrier();
  rdB(0, 0, bA);                                     // b01 of tile 0

  #pragma unroll
  for (int T = 0; T < NT; ++T)                       // FULL unroll: T compile-time
    tileStep(T, T & 1, (T & 1) ^ 1);

  if constexpr (SOFTMAX) {
    // logits = acc/4; softmax over the wave's 64-col block (= one head block)
    unsigned short* attn = reinterpret_cast<unsigned short*>(Cout);
    constexpr float CEXP = 0.25f * 1.44269504088896340736f; // log2(e)/4
    #pragma unroll
    for (int m = 0; m < 8; ++m) {
      const int row = brow + wm * 128 + m * 16 + fq * 4;
      #pragma unroll
      for (int j = 0; j < 4; ++j) {
        float v0 = acc[m][0][j], v1 = acc[m][1][j];
        float v2 = acc[m][2][j], v3 = acc[m][3][j];
        float mx = fmaxf(fmaxf(v0, v1), fmaxf(v2, v3));
        #pragma unroll
        for (int s = 1; s < 16; s <<= 1) mx = fmaxf(mx, __shfl_xor(mx, s, 64));
        float p0 = exp2f((v0 - mx) * CEXP);
        float p1 = exp2f((v1 - mx) * CEXP);
        float p2 = exp2f((v2 - mx) * CEXP);
        float p3 = exp2f((v3 - mx) * CEXP);
        float sm = p0 + p1 + p2 + p3;
        #pragma unroll
        for (int s = 1; s < 16; s <<= 1) sm += __shfl_xor(sm, s, 64);
        const float inv = 1.0f / sm;
        unsigned short* dst =
            attn + (size_t)(row + j) * ND + (bcol + wn * 64 + fr);
        dst[0]  = f2bf_rne(p0 * inv);
        dst[16] = f2bf_rne(p1 * inv);
        dst[32] = f2bf_rne(p2 * inv);
        dst[48] = f2bf_rne(p3 * inv);
      }
    }
  } else {
    // Vectorized f32 C-write via wave-private 16KB LDS bounce (r15).
    float* Cf = reinterpret_cast<float*>(Cout);
    char* wlds = ldsc + wid * 16384;
    #pragma unroll
    for (int h = 0; h < 2; ++h) {
      asm volatile("" ::: "memory");
      #pragma unroll
      for (int mm = 0; mm < 4; ++mm)
        #pragma unroll
        for (int n = 0; n < 4; ++n)
          #pragma unroll
          for (int j = 0; j < 4; ++j)
            *(float*)(wlds + (((mm * 16 + fq * 4 + j) << 6) + n * 16 + fr) * 4)
                = acc[4 * h + mm][n][j];
      asm volatile("s_waitcnt lgkmcnt(0)" ::: "memory"); // scatter visible
      const int rbase = brow + wm * 128 + h * 64;
      #pragma unroll
      for (int i = 0; i < 16; ++i) {
        const int idx16 = i * 64 + lane;     // 16B chunk id within 64x64 tile
        const int rl = idx16 >> 4;
        const int c4 = (idx16 & 15) << 2;
        f32x4 v = *(const f32x4*)(wlds + (size_t)idx16 * 16);
        *(f32x4*)(&Cf[(size_t)(rbase + rl) * ND + (bcol + wn * 64 + c4)]) = v;
      }
      asm volatile("s_waitcnt lgkmcnt(0)" ::: "memory"); // gather done pre-overwrite
    }
  }
}

extern "C" void kernel_launch(void* const* d_in, const int* in_sizes, int n_in,
                              void* d_out, int out_size, void* d_ws, size_t ws_size,
                              hipStream_t stream) {
  const float* x  = (const float*)d_in[0];   // [4,8192,1024] f32
  const float* W1 = (const float*)d_in[1];   // [3072,1024]  f32 (rows 0..1023 = Wq)
  const float* W2 = (const float*)d_in[2];   // [1024,1024]  f32
  float* out = (float*)d_out;

  char* ws = (char*)d_ws;
  unsigned short* xb   = (unsigned short*)(ws);
  unsigned short* w1b  = (unsigned short*)(ws + (size_t)67108864);
  unsigned short* w2b  = (unsigned short*)(ws + (size_t)69206016);
  unsigned short* attn = (unsigned short*)(ws + (size_t)71303168);

  hipFuncSetAttribute(reinterpret_cast<const void*>(gemm8<1>),
                      hipFuncAttributeMaxDynamicSharedMemorySize, 131072);
  hipFuncSetAttribute(reinterpret_cast<const void*>(gemm8<0>),
                      hipFuncAttributeMaxDynamicSharedMemorySize, 131072);

  cast_all<<<2048, 256, 0, stream>>>(x, W1, W2, xb, w1b, w2b);

  const int nblk = (MTOT / BM) * (ND / BN);   // 128 * 4 = 512
  gemm8<1><<<nblk, 512, 131072, stream>>>(xb, w1b, (void*)attn);
  gemm8<0><<<nblk, 512, 131072, stream>>>(attn, w2b, (void*)out);
}

// Round 23
// 179.529 us; speedup vs baseline: 1.0232x; 1.0232x over previous
//
#include <hip/hip_runtime.h>
#include <hip/hip_bf16.h>
#include <stdint.h>

// B=4, S=8192, E=1024, heads=16 -> math collapses to:
//   Q = x @ W1[0:1024].T ; A = per-64-col-block softmax(Q/4) ; out = A @ W2.T
// FINAL (r23 = r21, session best 181.2us): 269.8 -> 181.2 us over the session.
// Structure: 256x256 tile, BK=64, 8 waves (2Mx4N), 128 KiB dbuf LDS,
// T1 XCD swizzle, T2 LDS swizzle, global_load_lds width-16 staging,
// counted vmcnt (never 0 in loop), 3 barriers/K-tile, setprio (A/B-verified
// +2% on THIS structure, r21 vs r22), FULL K-loop unroll + hoisted
// lane-constant read-swizzle (+4%, r21), fused per-head softmax epilogue,
// LDS-bounce vectorized f32 C-write, single merged cast kernel.
static constexpr int MTOT = 32768;
static constexpr int KD   = 1024;
static constexpr int ND   = 1024;

static constexpr int BM = 256, BN = 256, BK = 64;
static constexpr int NT = KD / BK;              // 16 K-tiles (even)
static constexpr int BUF_BYTES = 65536;         // per-buffer: A 32K + B 32K
static constexpr int BOFF = 32768;              // B offset within buffer
static constexpr int HALF = 16384;              // one unit (128 rows x 64 cols bf16)

typedef __bf16 bf16x8 __attribute__((ext_vector_type(8)));
typedef float  f32x4  __attribute__((ext_vector_type(4)));

__device__ __forceinline__ unsigned short f2bf_rne(float f) {
  union { float f; uint32_t u; } c; c.f = f;
  uint32_t u = c.u;
  return (unsigned short)((u + 0x7fffu + ((u >> 16) & 1u)) >> 16);
}

// One kernel for all three casts (x, W1q, W2).
__global__ void cast_all(const float* __restrict__ x,
                         const float* __restrict__ W1,
                         const float* __restrict__ W2,
                         unsigned short* __restrict__ xb,
                         unsigned short* __restrict__ w1b,
                         unsigned short* __restrict__ w2b) {
  constexpr int n4x = MTOT * KD / 4;
  constexpr int n4w = KD * KD / 4;
  constexpr int total = n4x + 2 * n4w;
  int idx = blockIdx.x * blockDim.x + threadIdx.x;
  int stride = gridDim.x * blockDim.x;
  for (int i = idx; i < total; i += stride) {
    const float* s; unsigned short* d; int j;
    if (i < n4x)            { s = x;  d = xb;  j = i; }
    else if (i < n4x + n4w) { s = W1; d = w1b; j = i - n4x; }
    else                    { s = W2; d = w2b; j = i - n4x - n4w; }
    float4 v = reinterpret_cast<const float4*>(s)[j];
    ushort4 o;
    o.x = f2bf_rne(v.x); o.y = f2bf_rne(v.y);
    o.z = f2bf_rne(v.z); o.w = f2bf_rne(v.w);
    reinterpret_cast<ushort4*>(d)[j] = o;
  }
}

__device__ __forceinline__ void gload_lds16(const void* g, void* lds) {
  __builtin_amdgcn_global_load_lds(
      (const __attribute__((address_space(1))) unsigned int*)g,
      (__attribute__((address_space(3))) unsigned int*)lds, 16, 0, 0);
}

template <int SOFTMAX>
__global__ __launch_bounds__(512, 2)
void gemm8(const unsigned short* __restrict__ A,
           const unsigned short* __restrict__ Bm,
           void* __restrict__ Cout) {
  extern __shared__ __align__(16) char ldsc[];

  const int tid  = threadIdx.x;
  const int lane = tid & 63;
  const int wid  = tid >> 6;
  const int wm = wid >> 2, wn = wid & 3;       // wave tile: 128 rows x 64 cols
  const int fr = lane & 15, fq = lane >> 4;

  // T1: bijective XCD swizzle (512 blocks, 8 XCDs, 64 blocks/chunk).
  const int bid0 = blockIdx.x;
  const int bid  = ((bid0 & 7) << 6) | (bid0 >> 3);
  const int brow = (bid >> 2) * BM;
  const int bcol = (bid & 3) * BN;

  // staging: linear LDS dest + inverse-swizzled global src (rule #21).
  const int srow  = tid >> 3;                              // 0..63
  const int sslot = (tid & 7) ^ (srow & 7);
  const unsigned short* gA = A  + (size_t)(brow + srow) * KD + sslot * 8;
  const unsigned short* gB = Bm + (size_t)(bcol + srow) * KD + sslot * 8;

  // Hoisted lane-constant read-swizzle offsets.
  const int swzk0 = (fq * 16) ^ ((fr & 7) << 4);          // ks = 0
  const int swzk1 = (64 + fq * 16) ^ ((fr & 7) << 4);     // ks = 1

  f32x4  acc[8][4] = {};
  bf16x8 a0[4][2], a1[4][2], bA[2][2], bB[2][2];

  auto STAGE = [&](const unsigned short* g, int h, int kt, int b, int opOff) {
    const unsigned short* gu = g + (size_t)(h * 128) * KD + kt * BK;
    char* du = ldsc + b * BUF_BYTES + opOff + h * HALF + (wid << 10);
    gload_lds16(gu, du);
    gload_lds16(gu + (size_t)64 * KD, du + 8192);
  };

  auto rdA = [&](int b, bf16x8 (*dst)[2], int mBase) {
    const char* base = ldsc + b * BUF_BYTES + wm * HALF + (fr << 7);
    #pragma unroll
    for (int mm = 0; mm < 4; ++mm) {
      dst[mm][0] = *(const bf16x8*)(base + (mBase + mm) * 2048 + swzk0);
      dst[mm][1] = *(const bf16x8*)(base + (mBase + mm) * 2048 + swzk1);
    }
  };
  auto rdB = [&](int b, int nBase, bf16x8 (*dst)[2]) {
    const char* base = ldsc + b * BUF_BYTES + BOFF + (wn >> 1) * HALF +
                       (((wn & 1) * 64 + fr) << 7);
    #pragma unroll
    for (int nn = 0; nn < 2; ++nn) {
      dst[nn][0] = *(const bf16x8*)(base + (nBase + nn) * 2048 + swzk0);
      dst[nn][1] = *(const bf16x8*)(base + (nBase + nn) * 2048 + swzk1);
    }
  };
  auto MFMA16 = [&](int mBase, int nBase, bf16x8 (*af)[2], bf16x8 (*bf)[2]) {
    __builtin_amdgcn_s_setprio(1);
    #pragma unroll
    for (int ks = 0; ks < 2; ++ks)
      #pragma unroll
      for (int mm = 0; mm < 4; ++mm)
        #pragma unroll
        for (int nn = 0; nn < 2; ++nn)
          acc[mBase + mm][nBase + nn] = __builtin_amdgcn_mfma_f32_16x16x32_bf16(
              af[mm][ks], bf[nn][ks], acc[mBase + mm][nBase + nn], 0, 0, 0);
    __builtin_amdgcn_s_setprio(0);
  };

  // K-tile step. Barriers: P2-end, P4-pre(post-vmcnt), P4-end.
  auto tileStep = [&](int T, int cur, int nxt) {
    const int tp1 = (T + 1 < NT) ? T + 1 : NT - 1;   // compile-time (unrolled)
    const int tp2 = (T + 2 < NT) ? T + 2 : NT - 1;

    rdA(cur, a0, 0);
    STAGE(gB, 0, tp1, nxt, BOFF);
    MFMA16(0, 0, a0, bA);

    rdA(cur, a1, 4);
    STAGE(gB, 1, tp1, nxt, BOFF);
    MFMA16(4, 0, a1, bA);
    __builtin_amdgcn_s_barrier();            // P2-end: all cur.A reads retired

    rdB(cur, 2, bB);
    STAGE(gA, 0, tp2, cur, 0);
    MFMA16(4, 2, a1, bB);

    STAGE(gA, 1, tp2, cur, 0);
    asm volatile("s_waitcnt vmcnt(4)" ::: "memory"); // retires thru T+1; T+2.A flies
    __builtin_amdgcn_s_barrier();            // P4-pre: tile T+1 visible to all
    rdB(nxt, 0, bA);                         // tile T+1 b01; overlaps MFMA below
    MFMA16(0, 2, a0, bB);
    __builtin_amdgcn_s_barrier();            // P4-end
  };

  // --- prologue: tile0 (4 units) + A halves of tile1 ---
  STAGE(gA, 0, 0, 0, 0);    STAGE(gA, 1, 0, 0, 0);
  STAGE(gB, 0, 0, 0, BOFF); STAGE(gB, 1, 0, 0, BOFF);
  STAGE(gA, 0, 1, 1, 0);    STAGE(gA, 1, 1, 1, 0);
  asm volatile("s_waitcnt vmcnt(4)" ::: "memory");   // tile0 landed; A(1) in flight
  __builtin_amdgcn_s_barrier();
  rdB(0, 0, bA);                                     // b01 of tile 0

  #pragma unroll
  for (int T = 0; T < NT; ++T)                       // FULL unroll: T compile-time
    tileStep(T, T & 1, (T & 1) ^ 1);

  if constexpr (SOFTMAX) {
    // logits = acc/4; softmax over the wave's 64-col block (= one head block)
    unsigned short* attn = reinterpret_cast<unsigned short*>(Cout);
    constexpr float CEXP = 0.25f * 1.44269504088896340736f; // log2(e)/4
    #pragma unroll
    for (int m = 0; m < 8; ++m) {
      const int row = brow + wm * 128 + m * 16 + fq * 4;
      #pragma unroll
      for (int j = 0; j < 4; ++j) {
        float v0 = acc[m][0][j], v1 = acc[m][1][j];
        float v2 = acc[m][2][j], v3 = acc[m][3][j];
        float mx = fmaxf(fmaxf(v0, v1), fmaxf(v2, v3));
        #pragma unroll
        for (int s = 1; s < 16; s <<= 1) mx = fmaxf(mx, __shfl_xor(mx, s, 64));
        float p0 = exp2f((v0 - mx) * CEXP);
        float p1 = exp2f((v1 - mx) * CEXP);
        float p2 = exp2f((v2 - mx) * CEXP);
        float p3 = exp2f((v3 - mx) * CEXP);
        float sm = p0 + p1 + p2 + p3;
        #pragma unroll
        for (int s = 1; s < 16; s <<= 1) sm += __shfl_xor(sm, s, 64);
        const float inv = 1.0f / sm;
        unsigned short* dst =
            attn + (size_t)(row + j) * ND + (bcol + wn * 64 + fr);
        dst[0]  = f2bf_rne(p0 * inv);
        dst[16] = f2bf_rne(p1 * inv);
        dst[32] = f2bf_rne(p2 * inv);
        dst[48] = f2bf_rne(p3 * inv);
      }
    }
  } else {
    // Vectorized f32 C-write via wave-private 16KB LDS bounce.
    float* Cf = reinterpret_cast<float*>(Cout);
    char* wlds = ldsc + wid * 16384;
    #pragma unroll
    for (int h = 0; h < 2; ++h) {
      asm volatile("" ::: "memory");
      #pragma unroll
      for (int mm = 0; mm < 4; ++mm)
        #pragma unroll
        for (int n = 0; n < 4; ++n)
          #pragma unroll
          for (int j = 0; j < 4; ++j)
            *(float*)(wlds + (((mm * 16 + fq * 4 + j) << 6) + n * 16 + fr) * 4)
                = acc[4 * h + mm][n][j];
      asm volatile("s_waitcnt lgkmcnt(0)" ::: "memory"); // scatter visible
      const int rbase = brow + wm * 128 + h * 64;
      #pragma unroll
      for (int i = 0; i < 16; ++i) {
        const int idx16 = i * 64 + lane;     // 16B chunk id within 64x64 tile
        const int rl = idx16 >> 4;
        const int c4 = (idx16 & 15) << 2;
        f32x4 v = *(const f32x4*)(wlds + (size_t)idx16 * 16);
        *(f32x4*)(&Cf[(size_t)(rbase + rl) * ND + (bcol + wn * 64 + c4)]) = v;
      }
      asm volatile("s_waitcnt lgkmcnt(0)" ::: "memory"); // gather done pre-overwrite
    }
  }
}

extern "C" void kernel_launch(void* const* d_in, const int* in_sizes, int n_in,
                              void* d_out, int out_size, void* d_ws, size_t ws_size,
                              hipStream_t stream) {
  const float* x  = (const float*)d_in[0];   // [4,8192,1024] f32
  const float* W1 = (const float*)d_in[1];   // [3072,1024]  f32 (rows 0..1023 = Wq)
  const float* W2 = (const float*)d_in[2];   // [1024,1024]  f32
  float* out = (float*)d_out;

  char* ws = (char*)d_ws;
  unsigned short* xb   = (unsigned short*)(ws);
  unsigned short* w1b  = (unsigned short*)(ws + (size_t)67108864);
  unsigned short* w2b  = (unsigned short*)(ws + (size_t)69206016);
  unsigned short* attn = (unsigned short*)(ws + (size_t)71303168);

  hipFuncSetAttribute(reinterpret_cast<const void*>(gemm8<1>),
                      hipFuncAttributeMaxDynamicSharedMemorySize, 131072);
  hipFuncSetAttribute(reinterpret_cast<const void*>(gemm8<0>),
                      hipFuncAttributeMaxDynamicSharedMemorySize, 131072);

  cast_all<<<2048, 256, 0, stream>>>(x, W1, W2, xb, w1b, w2b);

  const int nblk = (MTOT / BM) * (ND / BN);   // 128 * 4 = 512
  gemm8<1><<<nblk, 512, 131072, stream>>>(xb, w1b, (void*)attn);
  gemm8<0><<<nblk, 512, 131072, stream>>>(attn, w2b, (void*)out);
}